// Round 19
// baseline (352.532 us; speedup 1.0000x reference)
//
#include <hip/hip_runtime.h>
#include <hip/hip_bf16.h>
#include <cstddef>
#include <cstdint>

#define D_MODELc 256
#define D_STATEc 16
#define D_INNERc 512
#define DT_RANKc 16
#define BATCHc   4
#define SEQLENc  4096
#define NCHUNK   128
#define CHUNK    32                   // NCHUNK*CHUNK == SEQLEN

typedef unsigned short u16;
typedef __attribute__((ext_vector_type(8))) short bf16x8;   // 8 bf16 (4 VGPR)
typedef __attribute__((ext_vector_type(4))) float f32x4;    // 4 f32 acc
typedef float __attribute__((ext_vector_type(4))) f4v;
typedef __attribute__((ext_vector_type(4))) uint32_t u32x4;

#define VMCNT6() asm volatile("s_waitcnt vmcnt(6)" ::: "memory")
#define VMCNT0() asm volatile("s_waitcnt vmcnt(0)" ::: "memory")

__device__ __forceinline__ float siluf(float v) { return v / (1.f + __expf(-v)); }

__device__ __forceinline__ u16 bf16_rne(float f) {
    uint32_t u = __float_as_uint(f);
    u += 0x7fffu + ((u >> 16) & 1u);
    return (u16)(u >> 16);
}
__device__ __forceinline__ float bf16_to_f(u16 h) {
    return __uint_as_float(((uint32_t)h) << 16);
}
__device__ __forceinline__ uint32_t pack_hl(float f) {      // split f -> (hi<<16)|lo
    u16 hh = bf16_rne(f);
    u16 ll = bf16_rne(f - bf16_to_f(hh));
    return ((uint32_t)hh << 16) | ll;
}
__device__ __forceinline__ float unpack_add(uint32_t v) {   // hi + lo
    return __uint_as_float(v & 0xFFFF0000u) + __uint_as_float(v << 16);
}
// 8 packed u32 -> hi-frag / lo-frag (bf16x8 each)
__device__ __forceinline__ void unpack_frag(const uint32_t* q, bf16x8& fh, bf16x8& fl) {
    union { bf16x8 v; uint32_t w[4]; } H, L;
    #pragma unroll
    for (int i = 0; i < 4; i++) {
        uint32_t a = q[2 * i], b = q[2 * i + 1];
        H.w[i] = (a >> 16) | (b & 0xFFFF0000u);
        L.w[i] = (a & 0xFFFFu) | (b << 16);
    }
    fh = H.v; fl = L.v;
}
// softplus, branchless, fast-math
__device__ __forceinline__ float softplusf(float x) {
    return fmaxf(x, 0.f) + __logf(1.f + __expf(-fabsf(x)));
}
// tree-reduced 16-term dot of xd row with w[16] (+bias), depth ~6
__device__ __forceinline__ float dot16_tree(const f4v x[4], const float* w, float bias) {
    float t0 = fmaf(x[0][1], w[1],  x[0][0] * w[0]);
    float t1 = fmaf(x[0][3], w[3],  x[0][2] * w[2]);
    float t2 = fmaf(x[1][1], w[5],  x[1][0] * w[4]);
    float t3 = fmaf(x[1][3], w[7],  x[1][2] * w[6]);
    float t4 = fmaf(x[2][1], w[9],  x[2][0] * w[8]);
    float t5 = fmaf(x[2][3], w[11], x[2][2] * w[10]);
    float t6 = fmaf(x[3][1], w[13], x[3][0] * w[12]);
    float t7 = fmaf(x[3][3], w[15], x[3][2] * w[14]);
    return bias + (((t0 + t1) + (t2 + t3)) + ((t4 + t5) + (t6 + t7)));
}
// q^(n+1) for n=0..15, depth-4 ladder (independent muls, fully unrolled)
__device__ __forceinline__ void qladder(float q, float* qd) {
    float q2 = q * q;
    float q4 = q2 * q2;
    float q8 = q4 * q4;
    qd[0] = q;        qd[1] = q2;       qd[2] = q2 * q;     qd[3] = q4;
    qd[4] = q4 * q;   qd[5] = q4 * q2;  qd[6] = q4 * qd[2]; qd[7] = q8;
    qd[8] = q8 * q;   qd[9] = q8 * q2;  qd[10] = q8 * qd[2]; qd[11] = q8 * q4;
    qd[12] = q8 * qd[4]; qd[13] = q8 * qd[5]; qd[14] = q8 * qd[6]; qd[15] = q8 * q8;
}

// global->LDS direct copy, 16B per lane; LDS dest = wave-uniform base + lane*16
#define GLL16(g, l) __builtin_amdgcn_global_load_lds( \
    (const __attribute__((address_space(1))) uint32_t*)(g), \
    (__attribute__((address_space(3))) uint32_t*)(l), 16, 0, 0)

// ---------------------------------------------------------------------------
// fused weight split: 5 f32 weights -> (hi, lo) bf16 pairs in one launch
// ---------------------------------------------------------------------------
__global__ __launch_bounds__(256) void split5_kernel(
        const float* __restrict__ s0, const float* __restrict__ s1,
        const float* __restrict__ s2, const float* __restrict__ s3,
        const float* __restrict__ s4,
        u16* __restrict__ h0, u16* __restrict__ l0,
        u16* __restrict__ h1, u16* __restrict__ l1,
        u16* __restrict__ h2, u16* __restrict__ l2,
        u16* __restrict__ h3, u16* __restrict__ l3,
        u16* __restrict__ h4, u16* __restrict__ l4,
        int n4w, int n4x) {
    const int which = blockIdx.y;
    const float* in; u16* hi; u16* lo; int n4;
    if      (which == 0) { in = s0; hi = h0; lo = l0; n4 = n4w; }
    else if (which == 1) { in = s1; hi = h1; lo = l1; n4 = n4w; }
    else if (which == 2) { in = s2; hi = h2; lo = l2; n4 = n4w; }
    else if (which == 3) { in = s3; hi = h3; lo = l3; n4 = n4x; }
    else                 { in = s4; hi = h4; lo = l4; n4 = n4x; }
    for (int i = blockIdx.x * 256 + threadIdx.x; i < n4; i += gridDim.x * 256) {
        float4 v = ((const float4*)in)[i];
        u16 a0 = bf16_rne(v.x), a1 = bf16_rne(v.y), a2 = bf16_rne(v.z), a3 = bf16_rne(v.w);
        ushort4 hv; hv.x = a0; hv.y = a1; hv.z = a2; hv.w = a3;
        ushort4 lv;
        lv.x = bf16_rne(v.x - bf16_to_f(a0));
        lv.y = bf16_rne(v.y - bf16_to_f(a1));
        lv.z = bf16_rne(v.z - bf16_to_f(a2));
        lv.w = bf16_rne(v.w - bf16_to_f(a3));
        ((ushort4*)hi)[i] = hv;
        ((ushort4*)lo)[i] = lv;
    }
}

// single-array split (for h, per batch-group)
__global__ __launch_bounds__(256) void split_kernel(const float* __restrict__ in,
                                                    u16* __restrict__ hi,
                                                    u16* __restrict__ lo, int n4) {
    int i = blockIdx.x * 256 + threadIdx.x;
    const int stride = gridDim.x * 256;
    for (; i < n4; i += stride) {
        float4 v = ((const float4*)in)[i];
        u16 a0 = bf16_rne(v.x), a1 = bf16_rne(v.y), a2 = bf16_rne(v.z), a3 = bf16_rne(v.w);
        ushort4 hv; hv.x = a0; hv.y = a1; hv.z = a2; hv.w = a3;
        ushort4 lv;
        lv.x = bf16_rne(v.x - bf16_to_f(a0));
        lv.y = bf16_rne(v.y - bf16_to_f(a1));
        lv.z = bf16_rne(v.z - bf16_to_f(a2));
        lv.w = bf16_rne(v.w - bf16_to_f(a3));
        ((ushort4*)hi)[i] = hv;
        ((ushort4*)lo)[i] = lv;
    }
}

// ---------------------------------------------------------------------------
// Split-bf16 MFMA NT GEMM, tile 128x64, BK=32, 4 waves (2x2: each 64x32),
// depth-2 counted-vmcnt pipeline. LDS: 2 x 24KB staging (A 16K + B 8K) = 48KB
// -> 3 blocks/CU (was 2 @64KB). Coalesced epilogue in two 64-row passes into
// a stride-66-padded u32[64][66] overlay (conflict-free: row-diff-4 -> bank
// shift 8, kgl groups disjoint). XCD-aware bijective remap (id&7 = XCD).
// AINT==0: A as separate Ah/Al bf16. AINT==1: A as interleaved u32.
// EPI==0: out0[m*N+n] = v (NT — final output)
// EPI==1: merged in-proj, N==2048 (NB=32, NBL2=5): dirn=nb>>4, sub=nb&15;
//         sub<8 -> uhl (pack(split(silu))), col (nb&7)*64
//         else  -> sz[m*1024+dirn*512+(nb&7)*64+col] = silu
// ---------------------------------------------------------------------------
template<int EPI, int NBL2, int AINT>
__global__ __launch_bounds__(256) void gemm_mfma(
        const u16* __restrict__ Ah, const u16* __restrict__ Al, int lda,
        const u16* __restrict__ Bh, const u16* __restrict__ Bl, int ldb,
        float* __restrict__ out0,
        uint32_t* __restrict__ uhl,
        int M, int N, int K) {
    __shared__ char lds[49152];
    const int t    = threadIdx.x;
    const int lane = t & 63;
    const int wid  = t >> 6;
    const int wrow = wid >> 1, wcol = wid & 1;

    // XCD-aware bijective remap (blocks = NB * (M/128), M/128 % 8 == 0)
    const int id  = blockIdx.x;
    const int xcd = id & 7;
    const int j   = id >> 3;
    const int nb  = j & ((1 << NBL2) - 1);
    const int mg  = j >> NBL2;
    const int m0  = (mg * 8 + xcd) * 128;
    const int n0  = nb * 64;

    const int lr  = lane & 15;       // frag row/col within 16
    const int kgl = lane >> 4;       // k-group 0..3

    f32x4 acc[4][2] = {};

    // hoisted staging pointers (6 chunks/thread; advance fixed stride/K-step)
    const char* gp[6];
    if (AINT == 0) {
        #pragma unroll
        for (int i = 0; i < 4; i++) {        // A chunks c=0..1023 (Ah, Al)
            int c    = i * 256 + t;
            int tile = c >> 9;               // 0 Ah, 1 Al
            int kg   = (c >> 7) & 3;
            int row  = c & 127;
            const u16* bsrc = tile ? Al : Ah;
            gp[i] = (const char*)(bsrc + (size_t)(m0 + row) * lda + kg * 8);
        }
    } else {
        #pragma unroll
        for (int i = 0; i < 4; i++) {        // A-int chunks c=0..1023
            int c    = i * 256 + t;
            int kg   = c >> 8;
            int row  = (c >> 1) & 127;
            int half = c & 1;
            gp[i] = (const char*)((const uint32_t*)Ah + (size_t)(m0 + row) * lda + kg * 8 + half * 4);
        }
    }
    #pragma unroll
    for (int i = 4; i < 6; i++) {            // B chunks cb=0..511 (Bh, Bl)
        int cb   = (i - 4) * 256 + t;
        int tile = cb >> 8;                  // 0 Bh, 1 Bl
        int kg   = (cb >> 6) & 3;
        int row  = cb & 63;
        const u16* bsrc = tile ? Bl : Bh;
        gp[i] = (const char*)(bsrc + (size_t)(n0 + row) * ldb + kg * 8);
    }
    const int ldst_t = t << 4;               // per-thread LDS byte offset

    auto stage = [&](int buf) {
        #pragma unroll
        for (int i = 0; i < 6; i++) {
            GLL16(gp[i], ((char*)lds) + buf * 24576 + i * 4096 + ldst_t);
            gp[i] += (AINT == 1 && i < 4) ? 128 : 64;   // bytes per K-step
        }
    };

    const int NT = K >> 5;
    stage(0);
    if (NT > 1) stage(1);

    for (int kt = 0; kt < NT; ++kt) {
        const int buf = kt & 1;
        if (kt + 1 < NT) { VMCNT6(); } else { VMCNT0(); }   // buf's loads landed
        __builtin_amdgcn_sched_barrier(0);
        __builtin_amdgcn_s_barrier();
        __builtin_amdgcn_sched_barrier(0);

        const char* lb = lds + buf * 24576;
        bf16x8 afh[4], afl[4];
        if (AINT == 0) {
            const u16* lbA = (const u16*)lb;
            #pragma unroll
            for (int mi = 0; mi < 4; mi++) {
                int row = wrow * 64 + mi * 16 + lr;
                afh[mi] = *(const bf16x8*)(lbA + kgl * 1024 + row * 8);          // Ah: kg stride 1024 u16
                afl[mi] = *(const bf16x8*)(lbA + 4096 + kgl * 1024 + row * 8);   // Al at +8KB
            }
        } else {
            const uint32_t* la = (const uint32_t*)lb;
            #pragma unroll
            for (int mi = 0; mi < 4; mi++) {
                int row = wrow * 64 + mi * 16 + lr;
                unpack_frag(la + kgl * 1024 + row * 8, afh[mi], afl[mi]);         // kg stride 1024 u32
            }
        }
        const u16* lbB = (const u16*)(lb + 16384);
        #pragma unroll
        for (int ni = 0; ni < 2; ni++) {
            int col = wcol * 32 + ni * 16 + lr;
            bf16x8 bfh = *(const bf16x8*)(lbB + kgl * 512 + col * 8);            // Bh: kg stride 512 u16
            bf16x8 bfl = *(const bf16x8*)(lbB + 2048 + kgl * 512 + col * 8);     // Bl at +4KB
            #pragma unroll
            for (int mi = 0; mi < 4; mi++) {
                acc[mi][ni] = __builtin_amdgcn_mfma_f32_16x16x32_bf16(afh[mi], bfh, acc[mi][ni], 0, 0, 0);
                acc[mi][ni] = __builtin_amdgcn_mfma_f32_16x16x32_bf16(afh[mi], bfl, acc[mi][ni], 0, 0, 0);
                acc[mi][ni] = __builtin_amdgcn_mfma_f32_16x16x32_bf16(afl[mi], bfh, acc[mi][ni], 0, 0, 0);
            }
        }
        __builtin_amdgcn_sched_barrier(0);
        __builtin_amdgcn_s_barrier();                        // all waves done READING buf
        __builtin_amdgcn_sched_barrier(0);
        if (kt + 2 < NT) stage(buf);                         // restage buf for kt+2
    }

    // ---- coalesced epilogue: two 64-row passes, padded stride 66 ----------
    uint32_t* lds32 = (uint32_t*)lds;
    const int dirn = (EPI == 1) ? (nb >> 4) : 0;
    const bool is_u = (EPI == 1) && ((nb & 15) < 8);
    const int colbase = (EPI == 1) ? (nb & 7) * 64 : 0;
    #pragma unroll
    for (int p = 0; p < 2; p++) {
        if (p == 1) __syncthreads();         // protect LDS between passes
        if (wrow == p) {
            #pragma unroll
            for (int mi = 0; mi < 4; mi++) {
                #pragma unroll
                for (int ni = 0; ni < 2; ni++) {
                    #pragma unroll
                    for (int r = 0; r < 4; r++) {
                        int row = mi * 16 + kgl * 4 + r;     // 0..63 within pass
                        int col = wcol * 32 + ni * 16 + lr;
                        float v = acc[mi][ni][r];
                        uint32_t w;
                        if (EPI == 0) w = __float_as_uint(v);
                        else {
                            float s = siluf(v);
                            w = is_u ? pack_hl(s) : __float_as_uint(s);
                        }
                        lds32[row * 66 + col] = w;
                    }
                }
            }
        }
        __syncthreads();
        // write out 64 rows x 64 cols: 1024 16B slots, 4 per thread
        #pragma unroll
        for (int i = 0; i < 4; i++) {
            int idx = i * 256 + t;
            int row = idx >> 4, c4 = idx & 15;
            int gm  = m0 + p * 64 + row;
            if (EPI == 0) {
                f4v v = *(const f4v*)(lds32 + row * 66 + c4 * 4);
                __builtin_nontemporal_store(v, (f4v*)(out0 + (size_t)gm * N + n0 + c4 * 4));
            } else if (is_u) {
                *(u32x4*)(uhl + (size_t)dirn * M * 512 + (size_t)gm * 512 + colbase + c4 * 4) =
                    *(const u32x4*)(lds32 + row * 66 + c4 * 4);
            } else {
                *(f4v*)(out0 + (size_t)gm * 1024 + (size_t)dirn * 512 + colbase + c4 * 4) =
                    *(const f4v*)(lds32 + row * 66 + c4 * 4);
            }
        }
    }
}

// ---------------------------------------------------------------------------
// xdbl MFMA GEMM, both dirs (blockIdx.y): xd[m,0..48) = sum_k u[m,k]*Wx[n,k].
// A = interleaved uhl (u32), hoisted staging pointers. M-tile 64, N=48, BK=32.
// ---------------------------------------------------------------------------
__global__ __launch_bounds__(256) void xdbl_mfma(
        const uint32_t* __restrict__ Uhl,
        const u16* __restrict__ WxH, const u16* __restrict__ WxL,
        float* __restrict__ out) {
    __shared__ uint32_t lds[4][64][8];   // 8 KB
    const int t    = threadIdx.x;
    const int lane = t & 63;
    const int wid  = t >> 6;
    const int m0   = blockIdx.x * 64;
    const int dir  = blockIdx.y;
    const int Mp   = gridDim.x * 64;
    const int lr   = lane & 15;
    const int kgl  = lane >> 4;

    const size_t dofU = (size_t)dir * (size_t)Mp * 512;
    const size_t dofW = (size_t)dir * (size_t)48 * 512;

    // hoisted staging pointers (advance 128 B per K-step)
    const char* gp[2];
    #pragma unroll
    for (int i = 0; i < 2; i++) {
        int c    = i * 256 + t;          // 0..511
        int kg   = c >> 7;
        int row  = (c >> 1) & 63;
        int half = c & 1;
        gp[i] = (const char*)(Uhl + dofU + (size_t)(m0 + row) * 512 + kg * 8 + half * 4);
    }
    const int ldst_t = t << 4;

    f32x4 acc[3] = {};

    for (int k0 = 0; k0 < 512; k0 += 32) {
        #pragma unroll
        for (int i = 0; i < 2; i++) {
            GLL16(gp[i], ((char*)lds) + i * 4096 + ldst_t);
            gp[i] += 128;
        }
        __syncthreads();

        bf16x8 afh, afl;
        unpack_frag(&lds[kgl][wid * 16 + lr][0], afh, afl);
        #pragma unroll
        for (int nf = 0; nf < 3; nf++) {
            const size_t boff = dofW + (size_t)(nf * 16 + lr) * 512 + k0 + kgl * 8;
            bf16x8 bfh = *(const bf16x8*)(WxH + boff);
            bf16x8 bfl = *(const bf16x8*)(WxL + boff);
            acc[nf] = __builtin_amdgcn_mfma_f32_16x16x32_bf16(afh, bfh, acc[nf], 0, 0, 0);
            acc[nf] = __builtin_amdgcn_mfma_f32_16x16x32_bf16(afh, bfl, acc[nf], 0, 0, 0);
            acc[nf] = __builtin_amdgcn_mfma_f32_16x16x32_bf16(afl, bfh, acc[nf], 0, 0, 0);
        }
        __syncthreads();
    }

    float* o = out + (size_t)dir * (size_t)Mp * 48;
    #pragma unroll
    for (int nf = 0; nf < 3; nf++) {
        #pragma unroll
        for (int r = 0; r < 4; r++) {
            int m = m0 + wid * 16 + kgl * 4 + r;
            int n = nf * 16 + lr;
            o[(size_t)m * 48 + n] = acc[nf][r];
        }
    }
}

// ---------------------------------------------------------------------------
// Chunked scan, both dirs merged (z = b*2 + dir).
// S layout: [z][chunk][n][d]; SDL: [z][chunk][d].
// ---------------------------------------------------------------------------
__global__ __launch_bounds__(256) void scan_phaseA(
        const uint32_t* __restrict__ Uhl,
        const float* __restrict__ XD,
        const float* __restrict__ Wdt_f, const float* __restrict__ Wdt_b,
        const float* __restrict__ bdt_f, const float* __restrict__ bdt_b,
        const float* __restrict__ AL_f, const float* __restrict__ AL_b,
        float* __restrict__ SDL, float* __restrict__ S) {
    const int c   = blockIdx.x;
    const int d   = blockIdx.y * 256 + threadIdx.x;
    const int z   = blockIdx.z;
    const int dir = z & 1;
    const int b   = z >> 1;
    const int PB  = gridDim.z >> 1;
    const int Mp  = PB * SEQLENc;
    const float* Wdt = dir ? Wdt_b : Wdt_f;
    const float* bdt = dir ? bdt_b : bdt_f;
    const float* AL  = dir ? AL_b  : AL_f;
    const uint32_t* UD = Uhl + (size_t)dir * Mp * 512;
    const float* XDD = XD + (size_t)dir * Mp * 48;

    float w[16], a[16], s[16];
    #pragma unroll
    for (int n = 0; n < 16; n++) {
        w[n] = Wdt[d * 16 + n];
        a[n] = -__expf(AL[d * 16 + n]);
        s[n] = 0.f;
    }
    const float a0 = a[0];
    bool pw = (a0 != 0.f);
    #pragma unroll
    for (int n = 1; n < 16; n++)
        pw = pw && (fabsf(a[n] - (float)(n + 1) * a0) <= 3e-6f * fabsf(a[n]));
    const float bb = bdt[d];
    float sdl = 0.f;

    for (int i = 0; i < CHUNK; i++) {
        int tt = c * CHUNK + i;
        int l  = dir ? (SEQLENc - 1 - tt) : tt;
        size_t row = (size_t)b * SEQLENc + l;
        float uu = unpack_add(UD[row * 512 + d]);
        const f4v* xr4 = (const f4v*)&XDD[row * 48];
        f4v xw[4] = {xr4[0], xr4[1], xr4[2], xr4[3]};
        float dl = softplusf(dot16_tree(xw, w, bb));
        sdl += dl;
        float du = dl * uu;
        if (pw) {
            float qd[16];
            qladder(__expf(a0 * dl), qd);
            #pragma unroll
            for (int g = 0; g < 4; g++) {
                f4v B4 = xr4[4 + g];
                #pragma unroll
                for (int jj = 0; jj < 4; jj++) {
                    int n = g * 4 + jj;
                    s[n] = fmaf(qd[n], s[n], du * B4[jj]);
                }
            }
        } else {
            #pragma unroll
            for (int g = 0; g < 4; g++) {
                f4v B4 = xr4[4 + g];
                #pragma unroll
                for (int jj = 0; jj < 4; jj++) {
                    int n = g * 4 + jj;
                    float dA = __expf(dl * a[n]);
                    s[n] = fmaf(dA, s[n], du * B4[jj]);
                }
            }
        }
    }
    SDL[((size_t)z * NCHUNK + c) * 512 + d] = sdl;
    size_t base = (((size_t)z * NCHUNK + c) * 16) * 512 + d;
    #pragma unroll
    for (int n = 0; n < 16; n++)
        S[base + (size_t)n * 512] = s[n];
}

// Serial over chunks; P recomputed from SDL (p = exp(a_n * sdl)).
// Overwrites S with the chunk ENTRY state.
__global__ __launch_bounds__(256) void scan_phaseB(const float* __restrict__ SDL,
                                                   float* __restrict__ S,
                                                   const float* __restrict__ AL_f,
                                                   const float* __restrict__ AL_b) {
    const int g   = blockIdx.x * 256 + threadIdx.x;
    const int d   = g & 511;
    const int n   = (g >> 9) & 15;
    const int z   = g >> 13;
    const int dir = z & 1;
    const float an = -__expf((dir ? AL_b : AL_f)[d * 16 + n]);
    const size_t strideS = (size_t)16 * 512;
    size_t offS = (((size_t)z * NCHUNK) * 16 + n) * 512 + d;
    size_t offD = ((size_t)z * NCHUNK) * 512 + d;
    float carry = 0.f;
    float sdl = SDL[offD], ss = S[offS];
    for (int c = 0; c < NCHUNK; c++) {
        float sdn = 0.f, sn = 0.f;
        if (c + 1 < NCHUNK) { sdn = SDL[offD + 512]; sn = S[offS + strideS]; }
        float pp = __expf(an * sdl);
        S[offS] = carry;               // entry state for chunk c
        carry = pp * carry + ss;
        sdl = sdn; ss = sn;
        offS += strideS; offD += 512;
    }
}

// scanC: reads sz[m][dir*512+d] then overwrites the SAME address with packed
// y (yhl aliases sz) — per-thread read-then-write, each address exactly once.
__global__ __launch_bounds__(256) void scan_phaseC(
        const uint32_t* __restrict__ Uhl,
        const float* __restrict__ XD,
        const float* __restrict__ Wdt_f, const float* __restrict__ Wdt_b,
        const float* __restrict__ bdt_f, const float* __restrict__ bdt_b,
        const float* __restrict__ AL_f, const float* __restrict__ AL_b,
        const float* __restrict__ E,    // entry states (in S buffer)
        const float* SZ,                // silu(z), [m][dir*512+d]
        const float* __restrict__ D_f,  const float* __restrict__ D_b,
        uint32_t* Yhl) {                // aliases SZ
    const int c   = blockIdx.x;
    const int d   = blockIdx.y * 256 + threadIdx.x;
    const int z   = blockIdx.z;
    const int dir = z & 1;
    const int b   = z >> 1;
    const int PB  = gridDim.z >> 1;
    const int Mp  = PB * SEQLENc;
    const float* Wdt = dir ? Wdt_b : Wdt_f;
    const float* bdt = dir ? bdt_b : bdt_f;
    const float* AL  = dir ? AL_b  : AL_f;
    const uint32_t* UD = Uhl + (size_t)dir * Mp * 512;
    const float* XDD = XD + (size_t)dir * Mp * 48;

    float w[16], a[16], s[16];
    size_t base = (((size_t)z * NCHUNK + c) * 16) * 512 + d;
    #pragma unroll
    for (int n = 0; n < 16; n++) {
        w[n] = Wdt[d * 16 + n];
        a[n] = -__expf(AL[d * 16 + n]);
        s[n] = E[base + (size_t)n * 512];
    }
    const float a0 = a[0];
    bool pw = (a0 != 0.f);
    #pragma unroll
    for (int n = 1; n < 16; n++)
        pw = pw && (fabsf(a[n] - (float)(n + 1) * a0) <= 3e-6f * fabsf(a[n]));
    const float bb = bdt[d];
    const float Dd = (dir ? D_b : D_f)[d];

    for (int i = 0; i < CHUNK; i++) {
        int tt = c * CHUNK + i;
        int l  = dir ? (SEQLENc - 1 - tt) : tt;
        size_t row = (size_t)b * SEQLENc + l;
        float uu = unpack_add(UD[row * 512 + d]);
        const f4v* xr4 = (const f4v*)&XDD[row * 48];
        f4v xw[4] = {xr4[0], xr4[1], xr4[2], xr4[3]};
        float dl = softplusf(dot16_tree(xw, w, bb));
        float du = dl * uu;
        float yp0 = 0.f, yp1 = 0.f, yp2 = 0.f, yp3 = 0.f;
        if (pw) {
            float qd[16];
            qladder(__expf(a0 * dl), qd);
            #pragma unroll
            for (int g = 0; g < 4; g++) {
                f4v B4 = xr4[4 + g];
                f4v C4 = xr4[8 + g];
                float yp = 0.f;
                #pragma unroll
                for (int jj = 0; jj < 4; jj++) {
                    int n = g * 4 + jj;
                    s[n] = fmaf(qd[n], s[n], du * B4[jj]);
                    yp = fmaf(s[n], C4[jj], yp);
                }
                if (g == 0) yp0 = yp; else if (g == 1) yp1 = yp;
                else if (g == 2) yp2 = yp; else yp3 = yp;
            }
        } else {
            #pragma unroll
            for (int g = 0; g < 4; g++) {
                f4v B4 = xr4[4 + g];
                f4v C4 = xr4[8 + g];
                float yp = 0.f;
                #pragma unroll
                for (int jj = 0; jj < 4; jj++) {
                    int n = g * 4 + jj;
                    float dA = __expf(dl * a[n]);
                    s[n] = fmaf(dA, s[n], du * B4[jj]);
                    yp = fmaf(s[n], C4[jj], yp);
                }
                if (g == 0) yp0 = yp; else if (g == 1) yp1 = yp;
                else if (g == 2) yp2 = yp; else yp3 = yp;
            }
        }
        float y = (yp0 + yp1) + (yp2 + yp3);
        size_t zi = row * 1024 + (size_t)dir * 512 + d;
        float sz = SZ[zi];
        float yv = (y + uu * Dd) * sz;
        Yhl[zi] = pack_hl(yv);          // overwrite same address (alias of SZ)
    }
}

// ---------------------------------------------------------------------------
extern "C" void kernel_launch(void* const* d_in, const int* in_sizes, int n_in,
                              void* d_out, int out_size, void* d_ws, size_t ws_size,
                              hipStream_t stream) {
    const float* h    = (const float*)d_in[0];
    const float* Wi_f = (const float*)d_in[1];
    const float* Wi_b = (const float*)d_in[2];
    const float* Wx_f = (const float*)d_in[3];
    const float* Wx_b = (const float*)d_in[4];
    const float* Wdt_f= (const float*)d_in[5];
    const float* Wdt_b= (const float*)d_in[6];
    const float* bdt_f= (const float*)d_in[7];
    const float* bdt_b= (const float*)d_in[8];
    const float* Al_f = (const float*)d_in[9];
    const float* Al_b = (const float*)d_in[10];
    const float* D_f  = (const float*)d_in[11];
    const float* D_b  = (const float*)d_in[12];
    const float* Wo   = (const float*)d_in[13];
    float* out = (float*)d_out;

    // ---- workspace layout --------------------------------------------------
    const size_t W_ELE  = 1024 * 256;                 // Wi per dir / Wo elements
    const size_t WX_ELE = 48 * 512;                   // Wx per dir
    const size_t FB   = (size_t)SEQLENc * D_INNERc;   // per-batch 512-wide
    const size_t FH   = (size_t)SEQLENc * D_MODELc;   // per-batch 256-wide
    const size_t FX   = (size_t)SEQLENc * 48;
    const size_t FP   = (size_t)NCHUNK * 16 * 512;    // S per batch-dir
    const size_t FD   = (size_t)NCHUNK * 512;         // SDL per batch-dir

    const size_t fixed_bytes = (8 * W_ELE + 4 * WX_ELE) * sizeof(u16);
    const size_t per_b = 2 * FH * sizeof(u16)                  // h hi/lo
                       + 2 * FB * sizeof(float)                // sz / yhl (shared)
                       + 2 * FB * sizeof(uint32_t)             // uhl (2 dirs)
                       + 2 * FX * sizeof(float)                // xd (2 dirs)
                       + 2 * (FP + FD) * sizeof(float);        // S + SDL (2 dirs)
    int PB = 4;
    if (fixed_bytes + 4 * per_b + 65536 > ws_size) PB = 2;
    if (fixed_bytes + 2 * per_b + 65536 > ws_size) PB = 1;

    char* cur = (char*)d_ws;
    auto alloc = [&](size_t bytes) -> char* {
        char* p = cur; cur += (bytes + 255) & ~(size_t)255; return p;
    };
    u16* WiH = (u16*)alloc(2 * W_ELE * 2);   // both dirs concatenated (2048x256)
    u16* WiL = (u16*)alloc(2 * W_ELE * 2);
    u16* WoH = (u16*)alloc(W_ELE * 2);
    u16* WoL = (u16*)alloc(W_ELE * 2);
    u16* WxH = (u16*)alloc(2 * WX_ELE * 2);  // both dirs concatenated
    u16* WxL = (u16*)alloc(2 * WX_ELE * 2);
    u16*      hH  = (u16*)alloc((size_t)PB * FH * 2);
    u16*      hL  = (u16*)alloc((size_t)PB * FH * 2);
    float*    sz  = (float*)alloc((size_t)PB * 2 * FB * 4);   // aliased by yhl
    uint32_t* uhl = (uint32_t*)alloc((size_t)PB * 2 * FB * 4);
    float*    xd  = (float*)alloc((size_t)PB * 2 * FX * 4);
    float*    SDL = (float*)alloc((size_t)PB * 2 * FD * 4);
    float*    S   = (float*)alloc((size_t)PB * 2 * FP * 4);
    uint32_t* yhl = (uint32_t*)sz;           // ALIAS: scanC converts sz -> y in place

    // ---- pre-split all weights in ONE launch ------------------------------
    {
        int n4w = (int)(W_ELE / 4);      // 65536
        int n4x = (int)(WX_ELE / 4);     // 6144
        split5_kernel<<<dim3(64, 5), 256, 0, stream>>>(
            Wi_f, Wi_b, Wo, Wx_f, Wx_b,
            WiH, WiL, WiH + W_ELE, WiL + W_ELE, WoH, WoL,
            WxH, WxL, WxH + WX_ELE, WxL + WX_ELE,
            n4w, n4x);
    }

    for (int b0 = 0; b0 < BATCHc; b0 += PB) {
        const int Mp = PB * SEQLENc;
        const int MB = Mp / 128;                     // multiple of 8 for all PB
        const float* hB = h   + (size_t)b0 * FH;
        float*       oB = out + (size_t)b0 * FH;

        {   // split h for this batch group
            int n4 = (int)((size_t)PB * FH / 4);
            int blocks = (n4 + 255) / 256; if (blocks > 2048) blocks = 2048;
            split_kernel<<<blocks, 256, 0, stream>>>(hB, hH, hL, n4);
        }

        // merged in-projection for BOTH dirs: N=2048, 64-wide n-tiles (NB=32)
        gemm_mfma<1, 5, 0><<<32 * MB, 256, 0, stream>>>(
            hH, hL, D_MODELc, WiH, WiL, D_MODELc,
            sz, uhl, Mp, 2048, D_MODELc);

        // xdbl for both dirs (A = interleaved uhl)
        xdbl_mfma<<<dim3(Mp / 64, 2), 256, 0, stream>>>(uhl, WxH, WxL, xd);

        // scans, both dirs merged (z = b*2 + dir)
        scan_phaseA<<<dim3(NCHUNK, 2, 2 * PB), 256, 0, stream>>>(
            uhl, xd, Wdt_f, Wdt_b, bdt_f, bdt_b, Al_f, Al_b, SDL, S);
        scan_phaseB<<<PB * 64, 256, 0, stream>>>(SDL, S, Al_f, Al_b);
        scan_phaseC<<<dim3(NCHUNK, 2, 2 * PB), 256, 0, stream>>>(
            uhl, xd, Wdt_f, Wdt_b, bdt_f, bdt_b, Al_f, Al_b,
            S, sz, D_f, D_b, yhl);

        // single fused out-projection: K=1024, N=256, 64-wide n-tiles (NB=4)
        gemm_mfma<0, 2, 1><<<4 * MB, 256, 0, stream>>>(
            (const u16*)yhl, nullptr, 1024, WoH, WoL, 1024,
            oB, nullptr, Mp, D_MODELc, 1024);
    }
}

// Round 20
// 316.912 us; speedup vs baseline: 1.1124x; 1.1124x over previous
//
#include <hip/hip_runtime.h>
#include <hip/hip_bf16.h>
#include <cstddef>
#include <cstdint>

#define D_MODELc 256
#define D_STATEc 16
#define D_INNERc 512
#define DT_RANKc 16
#define BATCHc   4
#define SEQLENc  4096
#define NCHUNK   128
#define CHUNK    32                   // NCHUNK*CHUNK == SEQLEN

typedef unsigned short u16;
typedef __attribute__((ext_vector_type(8))) short bf16x8;   // 8 bf16 (4 VGPR)
typedef __attribute__((ext_vector_type(4))) float f32x4;    // 4 f32 acc
typedef float __attribute__((ext_vector_type(4))) f4v;
typedef __attribute__((ext_vector_type(4))) uint32_t u32x4;

#define VMCNT8() asm volatile("s_waitcnt vmcnt(8)" ::: "memory")
#define VMCNT0() asm volatile("s_waitcnt vmcnt(0)" ::: "memory")

__device__ __forceinline__ float siluf(float v) { return v / (1.f + __expf(-v)); }

__device__ __forceinline__ u16 bf16_rne(float f) {
    uint32_t u = __float_as_uint(f);
    u += 0x7fffu + ((u >> 16) & 1u);
    return (u16)(u >> 16);
}
__device__ __forceinline__ float bf16_to_f(u16 h) {
    return __uint_as_float(((uint32_t)h) << 16);
}
__device__ __forceinline__ uint32_t pack_hl(float f) {      // split f -> (hi<<16)|lo
    u16 hh = bf16_rne(f);
    u16 ll = bf16_rne(f - bf16_to_f(hh));
    return ((uint32_t)hh << 16) | ll;
}
__device__ __forceinline__ float unpack_add(uint32_t v) {   // hi + lo
    return __uint_as_float(v & 0xFFFF0000u) + __uint_as_float(v << 16);
}
// 8 packed u32 -> hi-frag / lo-frag (bf16x8 each)
__device__ __forceinline__ void unpack_frag(const uint32_t* q, bf16x8& fh, bf16x8& fl) {
    union { bf16x8 v; uint32_t w[4]; } H, L;
    #pragma unroll
    for (int i = 0; i < 4; i++) {
        uint32_t a = q[2 * i], b = q[2 * i + 1];
        H.w[i] = (a >> 16) | (b & 0xFFFF0000u);
        L.w[i] = (a & 0xFFFFu) | (b << 16);
    }
    fh = H.v; fl = L.v;
}
// softplus, branchless, fast-math
__device__ __forceinline__ float softplusf(float x) {
    return fmaxf(x, 0.f) + __logf(1.f + __expf(-fabsf(x)));
}
// tree-reduced 16-term dot of xd row with w[16] (+bias), depth ~6
__device__ __forceinline__ float dot16_tree(const f4v x[4], const float* w, float bias) {
    float t0 = fmaf(x[0][1], w[1],  x[0][0] * w[0]);
    float t1 = fmaf(x[0][3], w[3],  x[0][2] * w[2]);
    float t2 = fmaf(x[1][1], w[5],  x[1][0] * w[4]);
    float t3 = fmaf(x[1][3], w[7],  x[1][2] * w[6]);
    float t4 = fmaf(x[2][1], w[9],  x[2][0] * w[8]);
    float t5 = fmaf(x[2][3], w[11], x[2][2] * w[10]);
    float t6 = fmaf(x[3][1], w[13], x[3][0] * w[12]);
    float t7 = fmaf(x[3][3], w[15], x[3][2] * w[14]);
    return bias + (((t0 + t1) + (t2 + t3)) + ((t4 + t5) + (t6 + t7)));
}
// q^(n+1) for n=0..15, depth-4 ladder (independent muls, fully unrolled)
__device__ __forceinline__ void qladder(float q, float* qd) {
    float q2 = q * q;
    float q4 = q2 * q2;
    float q8 = q4 * q4;
    qd[0] = q;        qd[1] = q2;       qd[2] = q2 * q;     qd[3] = q4;
    qd[4] = q4 * q;   qd[5] = q4 * q2;  qd[6] = q4 * qd[2]; qd[7] = q8;
    qd[8] = q8 * q;   qd[9] = q8 * q2;  qd[10] = q8 * qd[2]; qd[11] = q8 * q4;
    qd[12] = q8 * qd[4]; qd[13] = q8 * qd[5]; qd[14] = q8 * qd[6]; qd[15] = q8 * q8;
}

// global->LDS direct copy, 16B per lane; LDS dest = wave-uniform base + lane*16
#define GLL16(g, l) __builtin_amdgcn_global_load_lds( \
    (const __attribute__((address_space(1))) uint32_t*)(g), \
    (__attribute__((address_space(3))) uint32_t*)(l), 16, 0, 0)

// ---------------------------------------------------------------------------
// fused weight split: 5 f32 weights -> (hi, lo) bf16 pairs in one launch
// ---------------------------------------------------------------------------
__global__ __launch_bounds__(256) void split5_kernel(
        const float* __restrict__ s0, const float* __restrict__ s1,
        const float* __restrict__ s2, const float* __restrict__ s3,
        const float* __restrict__ s4,
        u16* __restrict__ h0, u16* __restrict__ l0,
        u16* __restrict__ h1, u16* __restrict__ l1,
        u16* __restrict__ h2, u16* __restrict__ l2,
        u16* __restrict__ h3, u16* __restrict__ l3,
        u16* __restrict__ h4, u16* __restrict__ l4,
        int n4w, int n4x) {
    const int which = blockIdx.y;
    const float* in; u16* hi; u16* lo; int n4;
    if      (which == 0) { in = s0; hi = h0; lo = l0; n4 = n4w; }
    else if (which == 1) { in = s1; hi = h1; lo = l1; n4 = n4w; }
    else if (which == 2) { in = s2; hi = h2; lo = l2; n4 = n4w; }
    else if (which == 3) { in = s3; hi = h3; lo = l3; n4 = n4x; }
    else                 { in = s4; hi = h4; lo = l4; n4 = n4x; }
    for (int i = blockIdx.x * 256 + threadIdx.x; i < n4; i += gridDim.x * 256) {
        float4 v = ((const float4*)in)[i];
        u16 a0 = bf16_rne(v.x), a1 = bf16_rne(v.y), a2 = bf16_rne(v.z), a3 = bf16_rne(v.w);
        ushort4 hv; hv.x = a0; hv.y = a1; hv.z = a2; hv.w = a3;
        ushort4 lv;
        lv.x = bf16_rne(v.x - bf16_to_f(a0));
        lv.y = bf16_rne(v.y - bf16_to_f(a1));
        lv.z = bf16_rne(v.z - bf16_to_f(a2));
        lv.w = bf16_rne(v.w - bf16_to_f(a3));
        ((ushort4*)hi)[i] = hv;
        ((ushort4*)lo)[i] = lv;
    }
}

// single-array split (for h, per batch-group)
__global__ __launch_bounds__(256) void split_kernel(const float* __restrict__ in,
                                                    u16* __restrict__ hi,
                                                    u16* __restrict__ lo, int n4) {
    int i = blockIdx.x * 256 + threadIdx.x;
    const int stride = gridDim.x * 256;
    for (; i < n4; i += stride) {
        float4 v = ((const float4*)in)[i];
        u16 a0 = bf16_rne(v.x), a1 = bf16_rne(v.y), a2 = bf16_rne(v.z), a3 = bf16_rne(v.w);
        ushort4 hv; hv.x = a0; hv.y = a1; hv.z = a2; hv.w = a3;
        ushort4 lv;
        lv.x = bf16_rne(v.x - bf16_to_f(a0));
        lv.y = bf16_rne(v.y - bf16_to_f(a1));
        lv.z = bf16_rne(v.z - bf16_to_f(a2));
        lv.w = bf16_rne(v.w - bf16_to_f(a3));
        ((ushort4*)hi)[i] = hv;
        ((ushort4*)lo)[i] = lv;
    }
}

// ---------------------------------------------------------------------------
// Split-bf16 MFMA NT GEMM (r17 structure — best measured): tile 128x128,
// BK=32, 4 waves, depth-2 counted-vmcnt pipeline, LDS 2x32KB; coalesced
// epilogue via LDS-transpose u32[128][128] with XOR bank swizzle
// (col ^= ((row>>2)&3)<<4) — removes the r17-measured 4-way conflict
// (1.05M) at zero cost; remaining 2-way aliasing is free (m136).
// XCD-aware bijective remap (id&7 = XCD).
// AINT==0: A as separate Ah/Al bf16. AINT==1: A as interleaved u32.
// EPI==0: out0[m*N+n] = v (NT — final output)
// EPI==1: merged in-proj, N==2048 (NB=16): nb 0-3 uhl-dir0, 4-7 sz-dir0,
//         8-11 uhl-dir1, 12-15 sz-dir1; uhl = pack(split(silu)), sz = silu.
// ---------------------------------------------------------------------------
template<int EPI, int NBL2, int AINT>
__global__ __launch_bounds__(256) void gemm_mfma(
        const u16* __restrict__ Ah, const u16* __restrict__ Al, int lda,
        const u16* __restrict__ Bh, const u16* __restrict__ Bl, int ldb,
        float* __restrict__ out0,
        uint32_t* __restrict__ uhl,
        int M, int N, int K) {
    __shared__ char lds[2][32768];
    const int t    = threadIdx.x;
    const int lane = t & 63;
    const int wid  = t >> 6;
    const int wrow = wid >> 1, wcol = wid & 1;

    // XCD-aware bijective remap (blocks = NB * (M/128), M/128 % 8 == 0)
    const int id  = blockIdx.x;
    const int xcd = id & 7;
    const int j   = id >> 3;
    const int nb  = j & ((1 << NBL2) - 1);
    const int mg  = j >> NBL2;
    const int m0  = (mg * 8 + xcd) * 128;
    const int n0  = nb * 128;

    const int lr  = lane & 15;       // frag row/col within 16
    const int kgl = lane >> 4;       // k-group 0..3

    f32x4 acc[4][4] = {};

    // hoisted staging pointers (advance by fixed stride per K-step)
    const char* gp[8];
    if (AINT == 0) {
        #pragma unroll
        for (int i = 0; i < 8; i++) {
            int c    = i * 256 + t;          // 0..2047
            int tile = c >> 9;               // 0..3
            int kg   = (c >> 7) & 3;
            int row  = c & 127;
            const u16* bsrc = (tile == 0) ? Ah : (tile == 1) ? Al : (tile == 2) ? Bh : Bl;
            int r0 = (tile < 2) ? m0 : n0;
            int ld = (tile < 2) ? lda : ldb;
            gp[i] = (const char*)(bsrc + (size_t)(r0 + row) * ld + kg * 8);
        }
    } else {
        #pragma unroll
        for (int i = 0; i < 4; i++) {        // A-int chunks: c = 0..1023
            int c    = i * 256 + t;
            int kg   = c >> 8;
            int row  = (c >> 1) & 127;
            int half = c & 1;
            gp[i] = (const char*)((const uint32_t*)Ah + (size_t)(m0 + row) * lda + kg * 8 + half * 4);
        }
        #pragma unroll
        for (int i = 4; i < 8; i++) {        // B chunks: cb = 0..1023
            int cb   = (i - 4) * 256 + t;
            int tile = cb >> 9;              // 0 Bh, 1 Bl
            int kg   = (cb >> 7) & 3;
            int row  = cb & 127;
            const u16* bsrc = tile ? Bl : Bh;
            gp[i] = (const char*)(bsrc + (size_t)(n0 + row) * ldb + kg * 8);
        }
    }
    const int ldst_t = t << 4;               // per-thread LDS byte offset

    auto stage = [&](int buf) {
        #pragma unroll
        for (int i = 0; i < 8; i++) {
            GLL16(gp[i], ((char*)lds) + buf * 32768 + i * 4096 + ldst_t);
            gp[i] += (AINT == 1 && i < 4) ? 128 : 64;   // bytes per K-step
        }
    };

    const int NT = K >> 5;
    stage(0);
    if (NT > 1) stage(1);

    for (int kt = 0; kt < NT; ++kt) {
        const int buf = kt & 1;
        if (kt + 1 < NT) { VMCNT8(); } else { VMCNT0(); }   // buf's loads landed
        __builtin_amdgcn_sched_barrier(0);
        __builtin_amdgcn_s_barrier();
        __builtin_amdgcn_sched_barrier(0);

        bf16x8 afh[4], afl[4];
        if (AINT == 0) {
            const u16* lb = (const u16*)lds[buf];
            #pragma unroll
            for (int mi = 0; mi < 4; mi++) {
                int row = wrow * 64 + mi * 16 + lr;
                afh[mi] = *(const bf16x8*)(lb + 0 * 4096 + kgl * 1024 + row * 8);
                afl[mi] = *(const bf16x8*)(lb + 1 * 4096 + kgl * 1024 + row * 8);
            }
        } else {
            const uint32_t* la = (const uint32_t*)lds[buf];
            #pragma unroll
            for (int mi = 0; mi < 4; mi++) {
                int row = wrow * 64 + mi * 16 + lr;
                unpack_frag(la + kgl * 1024 + row * 8, afh[mi], afl[mi]);
            }
        }
        const u16* lbB = (const u16*)(lds[buf] + 16384);
        #pragma unroll
        for (int ni = 0; ni < 4; ni++) {
            int row = wcol * 64 + ni * 16 + lr;
            bf16x8 bfh = *(const bf16x8*)(lbB + 0 * 4096 + kgl * 1024 + row * 8);
            bf16x8 bfl = *(const bf16x8*)(lbB + 1 * 4096 + kgl * 1024 + row * 8);
            #pragma unroll
            for (int mi = 0; mi < 4; mi++) {
                acc[mi][ni] = __builtin_amdgcn_mfma_f32_16x16x32_bf16(afh[mi], bfh, acc[mi][ni], 0, 0, 0);
                acc[mi][ni] = __builtin_amdgcn_mfma_f32_16x16x32_bf16(afh[mi], bfl, acc[mi][ni], 0, 0, 0);
                acc[mi][ni] = __builtin_amdgcn_mfma_f32_16x16x32_bf16(afl[mi], bfh, acc[mi][ni], 0, 0, 0);
            }
        }
        __builtin_amdgcn_sched_barrier(0);
        __builtin_amdgcn_s_barrier();                        // all waves done READING buf
        __builtin_amdgcn_sched_barrier(0);
        if (kt + 2 < NT) stage(buf);                         // restage buf for kt+2
    }

    // ---- coalesced epilogue via LDS transpose (swizzled, conflict-free) ----
    uint32_t* lds32 = (uint32_t*)lds;
    {
        const int dirn = (EPI == 1) ? (nb >> 3) : 0;
        const bool is_u = (EPI == 1) && (((nb >> 2) & 1) == 0);
        // stage tile into LDS as row-major u32[128][128], col XOR-swizzled
        #pragma unroll
        for (int mi = 0; mi < 4; mi++) {
            #pragma unroll
            for (int ni = 0; ni < 4; ni++) {
                #pragma unroll
                for (int r = 0; r < 4; r++) {
                    int row = wrow * 64 + mi * 16 + kgl * 4 + r;
                    int col = wcol * 64 + ni * 16 + lr;
                    int swz = ((row >> 2) & 3) << 4;     // spreads kgl groups
                    float v = acc[mi][ni][r];
                    uint32_t w;
                    if (EPI == 0) w = __float_as_uint(v);
                    else {
                        float s = siluf(v);
                        w = is_u ? pack_hl(s) : __float_as_uint(s);
                    }
                    lds32[row * 128 + (col ^ swz)] = w;
                }
            }
        }
        __syncthreads();
        // 16 coalesced 16B stores per thread (waves emit contiguous 1KB runs)
        if (EPI == 0) {
            float* base = out0 + (size_t)m0 * N + n0;
            #pragma unroll
            for (int i = 0; i < 16; i++) {
                int idx = i * 256 + t;          // float4 slot 0..4095
                int row = idx >> 5, c4 = idx & 31;
                int swz = ((row >> 2) & 3) << 4;
                f4v v = *(const f4v*)(lds32 + row * 128 + ((c4 * 4) ^ swz));
                __builtin_nontemporal_store(v, (f4v*)(base + (size_t)row * N + c4 * 4));
            }
        } else {
            const int colbase = (nb & 3) * 128;
            if (is_u) {
                uint32_t* base = uhl + (size_t)dirn * M * 512 + (size_t)m0 * 512 + colbase;
                #pragma unroll
                for (int i = 0; i < 16; i++) {
                    int idx = i * 256 + t;
                    int row = idx >> 5, c4 = idx & 31;
                    int swz = ((row >> 2) & 3) << 4;
                    *(u32x4*)(base + (size_t)row * 512 + c4 * 4) =
                        *(const u32x4*)(lds32 + row * 128 + ((c4 * 4) ^ swz));
                }
            } else {
                float* base = out0 + (size_t)m0 * 1024 + (size_t)dirn * 512 + colbase;
                #pragma unroll
                for (int i = 0; i < 16; i++) {
                    int idx = i * 256 + t;
                    int row = idx >> 5, c4 = idx & 31;
                    int swz = ((row >> 2) & 3) << 4;
                    *(f4v*)(base + (size_t)row * 1024 + c4 * 4) =
                        *(const f4v*)(lds32 + row * 128 + ((c4 * 4) ^ swz));
                }
            }
        }
    }
}

// ---------------------------------------------------------------------------
// xdbl MFMA GEMM, both dirs (blockIdx.y): xd[m,0..48) = sum_k u[m,k]*Wx[n,k].
// A = interleaved uhl (u32), hoisted staging pointers. M-tile 64, N=48, BK=32.
// ---------------------------------------------------------------------------
__global__ __launch_bounds__(256) void xdbl_mfma(
        const uint32_t* __restrict__ Uhl,
        const u16* __restrict__ WxH, const u16* __restrict__ WxL,
        float* __restrict__ out) {
    __shared__ uint32_t lds[4][64][8];   // 8 KB
    const int t    = threadIdx.x;
    const int lane = t & 63;
    const int wid  = t >> 6;
    const int m0   = blockIdx.x * 64;
    const int dir  = blockIdx.y;
    const int Mp   = gridDim.x * 64;
    const int lr   = lane & 15;
    const int kgl  = lane >> 4;

    const size_t dofU = (size_t)dir * (size_t)Mp * 512;
    const size_t dofW = (size_t)dir * (size_t)48 * 512;

    // hoisted staging pointers (advance 128 B per K-step)
    const char* gp[2];
    #pragma unroll
    for (int i = 0; i < 2; i++) {
        int c    = i * 256 + t;          // 0..511
        int kg   = c >> 7;
        int row  = (c >> 1) & 63;
        int half = c & 1;
        gp[i] = (const char*)(Uhl + dofU + (size_t)(m0 + row) * 512 + kg * 8 + half * 4);
    }
    const int ldst_t = t << 4;

    f32x4 acc[3] = {};

    for (int k0 = 0; k0 < 512; k0 += 32) {
        #pragma unroll
        for (int i = 0; i < 2; i++) {
            GLL16(gp[i], ((char*)lds) + i * 4096 + ldst_t);
            gp[i] += 128;
        }
        __syncthreads();

        bf16x8 afh, afl;
        unpack_frag(&lds[kgl][wid * 16 + lr][0], afh, afl);
        #pragma unroll
        for (int nf = 0; nf < 3; nf++) {
            const size_t boff = dofW + (size_t)(nf * 16 + lr) * 512 + k0 + kgl * 8;
            bf16x8 bfh = *(const bf16x8*)(WxH + boff);
            bf16x8 bfl = *(const bf16x8*)(WxL + boff);
            acc[nf] = __builtin_amdgcn_mfma_f32_16x16x32_bf16(afh, bfh, acc[nf], 0, 0, 0);
            acc[nf] = __builtin_amdgcn_mfma_f32_16x16x32_bf16(afh, bfl, acc[nf], 0, 0, 0);
            acc[nf] = __builtin_amdgcn_mfma_f32_16x16x32_bf16(afl, bfh, acc[nf], 0, 0, 0);
        }
        __syncthreads();
    }

    float* o = out + (size_t)dir * (size_t)Mp * 48;
    #pragma unroll
    for (int nf = 0; nf < 3; nf++) {
        #pragma unroll
        for (int r = 0; r < 4; r++) {
            int m = m0 + wid * 16 + kgl * 4 + r;
            int n = nf * 16 + lr;
            o[(size_t)m * 48 + n] = acc[nf][r];
        }
    }
}

// ---------------------------------------------------------------------------
// Chunked scan, both dirs merged (z = b*2 + dir).
// S layout: [z][chunk][n][d]; SDL: [z][chunk][d].
// ---------------------------------------------------------------------------
__global__ __launch_bounds__(256) void scan_phaseA(
        const uint32_t* __restrict__ Uhl,
        const float* __restrict__ XD,
        const float* __restrict__ Wdt_f, const float* __restrict__ Wdt_b,
        const float* __restrict__ bdt_f, const float* __restrict__ bdt_b,
        const float* __restrict__ AL_f, const float* __restrict__ AL_b,
        float* __restrict__ SDL, float* __restrict__ S) {
    const int c   = blockIdx.x;
    const int d   = blockIdx.y * 256 + threadIdx.x;
    const int z   = blockIdx.z;
    const int dir = z & 1;
    const int b   = z >> 1;
    const int PB  = gridDim.z >> 1;
    const int Mp  = PB * SEQLENc;
    const float* Wdt = dir ? Wdt_b : Wdt_f;
    const float* bdt = dir ? bdt_b : bdt_f;
    const float* AL  = dir ? AL_b  : AL_f;
    const uint32_t* UD = Uhl + (size_t)dir * Mp * 512;
    const float* XDD = XD + (size_t)dir * Mp * 48;

    float w[16], a[16], s[16];
    #pragma unroll
    for (int n = 0; n < 16; n++) {
        w[n] = Wdt[d * 16 + n];
        a[n] = -__expf(AL[d * 16 + n]);
        s[n] = 0.f;
    }
    const float a0 = a[0];
    bool pw = (a0 != 0.f);
    #pragma unroll
    for (int n = 1; n < 16; n++)
        pw = pw && (fabsf(a[n] - (float)(n + 1) * a0) <= 3e-6f * fabsf(a[n]));
    const float bb = bdt[d];
    float sdl = 0.f;

    for (int i = 0; i < CHUNK; i++) {
        int tt = c * CHUNK + i;
        int l  = dir ? (SEQLENc - 1 - tt) : tt;
        size_t row = (size_t)b * SEQLENc + l;
        float uu = unpack_add(UD[row * 512 + d]);
        const f4v* xr4 = (const f4v*)&XDD[row * 48];
        f4v xw[4] = {xr4[0], xr4[1], xr4[2], xr4[3]};
        float dl = softplusf(dot16_tree(xw, w, bb));
        sdl += dl;
        float du = dl * uu;
        if (pw) {
            float qd[16];
            qladder(__expf(a0 * dl), qd);
            #pragma unroll
            for (int g = 0; g < 4; g++) {
                f4v B4 = xr4[4 + g];
                #pragma unroll
                for (int jj = 0; jj < 4; jj++) {
                    int n = g * 4 + jj;
                    s[n] = fmaf(qd[n], s[n], du * B4[jj]);
                }
            }
        } else {
            #pragma unroll
            for (int g = 0; g < 4; g++) {
                f4v B4 = xr4[4 + g];
                #pragma unroll
                for (int jj = 0; jj < 4; jj++) {
                    int n = g * 4 + jj;
                    float dA = __expf(dl * a[n]);
                    s[n] = fmaf(dA, s[n], du * B4[jj]);
                }
            }
        }
    }
    SDL[((size_t)z * NCHUNK + c) * 512 + d] = sdl;
    size_t base = (((size_t)z * NCHUNK + c) * 16) * 512 + d;
    #pragma unroll
    for (int n = 0; n < 16; n++)
        S[base + (size_t)n * 512] = s[n];
}

// Serial over chunks; P recomputed from SDL (p = exp(a_n * sdl)).
// Overwrites S with the chunk ENTRY state.
__global__ __launch_bounds__(256) void scan_phaseB(const float* __restrict__ SDL,
                                                   float* __restrict__ S,
                                                   const float* __restrict__ AL_f,
                                                   const float* __restrict__ AL_b) {
    const int g   = blockIdx.x * 256 + threadIdx.x;
    const int d   = g & 511;
    const int n   = (g >> 9) & 15;
    const int z   = g >> 13;
    const int dir = z & 1;
    const float an = -__expf((dir ? AL_b : AL_f)[d * 16 + n]);
    const size_t strideS = (size_t)16 * 512;
    size_t offS = (((size_t)z * NCHUNK) * 16 + n) * 512 + d;
    size_t offD = ((size_t)z * NCHUNK) * 512 + d;
    float carry = 0.f;
    float sdl = SDL[offD], ss = S[offS];
    for (int c = 0; c < NCHUNK; c++) {
        float sdn = 0.f, sn = 0.f;
        if (c + 1 < NCHUNK) { sdn = SDL[offD + 512]; sn = S[offS + strideS]; }
        float pp = __expf(an * sdl);
        S[offS] = carry;               // entry state for chunk c
        carry = pp * carry + ss;
        sdl = sdn; ss = sn;
        offS += strideS; offD += 512;
    }
}

// scanC: reads sz[m][dir*512+d] then overwrites the SAME address with packed
// y (yhl aliases sz) — per-thread read-then-write, each address exactly once.
__global__ __launch_bounds__(256) void scan_phaseC(
        const uint32_t* __restrict__ Uhl,
        const float* __restrict__ XD,
        const float* __restrict__ Wdt_f, const float* __restrict__ Wdt_b,
        const float* __restrict__ bdt_f, const float* __restrict__ bdt_b,
        const float* __restrict__ AL_f, const float* __restrict__ AL_b,
        const float* __restrict__ E,    // entry states (in S buffer)
        const float* SZ,                // silu(z), [m][dir*512+d]
        const float* __restrict__ D_f,  const float* __restrict__ D_b,
        uint32_t* Yhl) {                // aliases SZ
    const int c   = blockIdx.x;
    const int d   = blockIdx.y * 256 + threadIdx.x;
    const int z   = blockIdx.z;
    const int dir = z & 1;
    const int b   = z >> 1;
    const int PB  = gridDim.z >> 1;
    const int Mp  = PB * SEQLENc;
    const float* Wdt = dir ? Wdt_b : Wdt_f;
    const float* bdt = dir ? bdt_b : bdt_f;
    const float* AL  = dir ? AL_b  : AL_f;
    const uint32_t* UD = Uhl + (size_t)dir * Mp * 512;
    const float* XDD = XD + (size_t)dir * Mp * 48;

    float w[16], a[16], s[16];
    size_t base = (((size_t)z * NCHUNK + c) * 16) * 512 + d;
    #pragma unroll
    for (int n = 0; n < 16; n++) {
        w[n] = Wdt[d * 16 + n];
        a[n] = -__expf(AL[d * 16 + n]);
        s[n] = E[base + (size_t)n * 512];
    }
    const float a0 = a[0];
    bool pw = (a0 != 0.f);
    #pragma unroll
    for (int n = 1; n < 16; n++)
        pw = pw && (fabsf(a[n] - (float)(n + 1) * a0) <= 3e-6f * fabsf(a[n]));
    const float bb = bdt[d];
    const float Dd = (dir ? D_b : D_f)[d];

    for (int i = 0; i < CHUNK; i++) {
        int tt = c * CHUNK + i;
        int l  = dir ? (SEQLENc - 1 - tt) : tt;
        size_t row = (size_t)b * SEQLENc + l;
        float uu = unpack_add(UD[row * 512 + d]);
        const f4v* xr4 = (const f4v*)&XDD[row * 48];
        f4v xw[4] = {xr4[0], xr4[1], xr4[2], xr4[3]};
        float dl = softplusf(dot16_tree(xw, w, bb));
        float du = dl * uu;
        float yp0 = 0.f, yp1 = 0.f, yp2 = 0.f, yp3 = 0.f;
        if (pw) {
            float qd[16];
            qladder(__expf(a0 * dl), qd);
            #pragma unroll
            for (int g = 0; g < 4; g++) {
                f4v B4 = xr4[4 + g];
                f4v C4 = xr4[8 + g];
                float yp = 0.f;
                #pragma unroll
                for (int jj = 0; jj < 4; jj++) {
                    int n = g * 4 + jj;
                    s[n] = fmaf(qd[n], s[n], du * B4[jj]);
                    yp = fmaf(s[n], C4[jj], yp);
                }
                if (g == 0) yp0 = yp; else if (g == 1) yp1 = yp;
                else if (g == 2) yp2 = yp; else yp3 = yp;
            }
        } else {
            #pragma unroll
            for (int g = 0; g < 4; g++) {
                f4v B4 = xr4[4 + g];
                f4v C4 = xr4[8 + g];
                float yp = 0.f;
                #pragma unroll
                for (int jj = 0; jj < 4; jj++) {
                    int n = g * 4 + jj;
                    float dA = __expf(dl * a[n]);
                    s[n] = fmaf(dA, s[n], du * B4[jj]);
                    yp = fmaf(s[n], C4[jj], yp);
                }
                if (g == 0) yp0 = yp; else if (g == 1) yp1 = yp;
                else if (g == 2) yp2 = yp; else yp3 = yp;
            }
        }
        float y = (yp0 + yp1) + (yp2 + yp3);
        size_t zi = row * 1024 + (size_t)dir * 512 + d;
        float sz = SZ[zi];
        float yv = (y + uu * Dd) * sz;
        Yhl[zi] = pack_hl(yv);          // overwrite same address (alias of SZ)
    }
}

// ---------------------------------------------------------------------------
extern "C" void kernel_launch(void* const* d_in, const int* in_sizes, int n_in,
                              void* d_out, int out_size, void* d_ws, size_t ws_size,
                              hipStream_t stream) {
    const float* h    = (const float*)d_in[0];
    const float* Wi_f = (const float*)d_in[1];
    const float* Wi_b = (const float*)d_in[2];
    const float* Wx_f = (const float*)d_in[3];
    const float* Wx_b = (const float*)d_in[4];
    const float* Wdt_f= (const float*)d_in[5];
    const float* Wdt_b= (const float*)d_in[6];
    const float* bdt_f= (const float*)d_in[7];
    const float* bdt_b= (const float*)d_in[8];
    const float* Al_f = (const float*)d_in[9];
    const float* Al_b = (const float*)d_in[10];
    const float* D_f  = (const float*)d_in[11];
    const float* D_b  = (const float*)d_in[12];
    const float* Wo   = (const float*)d_in[13];
    float* out = (float*)d_out;

    // ---- workspace layout --------------------------------------------------
    const size_t W_ELE  = 1024 * 256;                 // Wi per dir / Wo elements
    const size_t WX_ELE = 48 * 512;                   // Wx per dir
    const size_t FB   = (size_t)SEQLENc * D_INNERc;   // per-batch 512-wide
    const size_t FH   = (size_t)SEQLENc * D_MODELc;   // per-batch 256-wide
    const size_t FX   = (size_t)SEQLENc * 48;
    const size_t FP   = (size_t)NCHUNK * 16 * 512;    // S per batch-dir
    const size_t FD   = (size_t)NCHUNK * 512;         // SDL per batch-dir

    const size_t fixed_bytes = (8 * W_ELE + 4 * WX_ELE) * sizeof(u16);
    const size_t per_b = 2 * FH * sizeof(u16)                  // h hi/lo
                       + 2 * FB * sizeof(float)                // sz / yhl (shared)
                       + 2 * FB * sizeof(uint32_t)             // uhl (2 dirs)
                       + 2 * FX * sizeof(float)                // xd (2 dirs)
                       + 2 * (FP + FD) * sizeof(float);        // S + SDL (2 dirs)
    int PB = 4;
    if (fixed_bytes + 4 * per_b + 65536 > ws_size) PB = 2;
    if (fixed_bytes + 2 * per_b + 65536 > ws_size) PB = 1;

    char* cur = (char*)d_ws;
    auto alloc = [&](size_t bytes) -> char* {
        char* p = cur; cur += (bytes + 255) & ~(size_t)255; return p;
    };
    u16* WiH = (u16*)alloc(2 * W_ELE * 2);   // both dirs concatenated (2048x256)
    u16* WiL = (u16*)alloc(2 * W_ELE * 2);
    u16* WoH = (u16*)alloc(W_ELE * 2);
    u16* WoL = (u16*)alloc(W_ELE * 2);
    u16* WxH = (u16*)alloc(2 * WX_ELE * 2);  // both dirs concatenated
    u16* WxL = (u16*)alloc(2 * WX_ELE * 2);
    u16*      hH  = (u16*)alloc((size_t)PB * FH * 2);
    u16*      hL  = (u16*)alloc((size_t)PB * FH * 2);
    float*    sz  = (float*)alloc((size_t)PB * 2 * FB * 4);   // aliased by yhl
    uint32_t* uhl = (uint32_t*)alloc((size_t)PB * 2 * FB * 4);
    float*    xd  = (float*)alloc((size_t)PB * 2 * FX * 4);
    float*    SDL = (float*)alloc((size_t)PB * 2 * FD * 4);
    float*    S   = (float*)alloc((size_t)PB * 2 * FP * 4);
    uint32_t* yhl = (uint32_t*)sz;           // ALIAS: scanC converts sz -> y in place

    // ---- pre-split all weights in ONE launch ------------------------------
    {
        int n4w = (int)(W_ELE / 4);      // 65536
        int n4x = (int)(WX_ELE / 4);     // 6144
        split5_kernel<<<dim3(64, 5), 256, 0, stream>>>(
            Wi_f, Wi_b, Wo, Wx_f, Wx_b,
            WiH, WiL, WiH + W_ELE, WiL + W_ELE, WoH, WoL,
            WxH, WxL, WxH + WX_ELE, WxL + WX_ELE,
            n4w, n4x);
    }

    for (int b0 = 0; b0 < BATCHc; b0 += PB) {
        const int Mp = PB * SEQLENc;
        const int MB = Mp / 128;                     // multiple of 8 for all PB
        const float* hB = h   + (size_t)b0 * FH;
        float*       oB = out + (size_t)b0 * FH;

        {   // split h for this batch group
            int n4 = (int)((size_t)PB * FH / 4);
            int blocks = (n4 + 255) / 256; if (blocks > 2048) blocks = 2048;
            split_kernel<<<blocks, 256, 0, stream>>>(hB, hH, hL, n4);
        }

        // merged in-projection for BOTH dirs: N=2048 (NB=16, NBL2=4)
        gemm_mfma<1, 4, 0><<<16 * MB, 256, 0, stream>>>(
            hH, hL, D_MODELc, WiH, WiL, D_MODELc,
            sz, uhl, Mp, 2048, D_MODELc);

        // xdbl for both dirs (A = interleaved uhl)
        xdbl_mfma<<<dim3(Mp / 64, 2), 256, 0, stream>>>(uhl, WxH, WxL, xd);

        // scans, both dirs merged (z = b*2 + dir)
        scan_phaseA<<<dim3(NCHUNK, 2, 2 * PB), 256, 0, stream>>>(
            uhl, xd, Wdt_f, Wdt_b, bdt_f, bdt_b, Al_f, Al_b, SDL, S);
        scan_phaseB<<<PB * 64, 256, 0, stream>>>(SDL, S, Al_f, Al_b);
        scan_phaseC<<<dim3(NCHUNK, 2, 2 * PB), 256, 0, stream>>>(
            uhl, xd, Wdt_f, Wdt_b, bdt_f, bdt_b, Al_f, Al_b,
            S, sz, D_f, D_b, yhl);

        // single fused out-projection: K=1024, N=256 (NB=2, NBL2=1), A=yhl
        gemm_mfma<0, 1, 1><<<2 * MB, 256, 0, stream>>>(
            (const u16*)yhl, nullptr, 1024, WoH, WoL, 1024,
            oB, nullptr, Mp, D_MODELc, 1024);
    }
}